// Round 4
// baseline (297.079 us; speedup 1.0000x reference)
//
#include <hip/hip_runtime.h>

#define B_ 4
#define N_ 4096
#define ROWS (B_ * N_)            // 16384 rows per side
#define PTS_TOTAL (2 * ROWS)      // 32768 points total

#define LOG2E 1.4426950408889634f
#define LN2   0.6931471805599453f
#define EPS1  1e-4f               /* BLUR^P */
#define NEG_LOG2M (-12.0f)        /* -log2(4096) */
#define ENC_STRIDE 32

typedef float f2 __attribute__((ext_vector_type(2)));

__device__ inline unsigned fenc(float f) {
  unsigned u = __float_as_uint(f);
  return (u & 0x80000000u) ? ~u : (u | 0x80000000u);
}
__device__ inline float fdec(unsigned u) {
  return (u & 0x80000000u) ? __uint_as_float(u & 0x7fffffffu)
                           : __uint_as_float(~u);
}
__device__ inline float fexp2(float x) { return __builtin_amdgcn_exp2f(x); }
__device__ inline float flog2(float x) { return __builtin_amdgcn_logf(x); }

__global__ void init_kernel(unsigned* enc) {
  if (threadIdx.x < 13) enc[threadIdx.x * ENC_STRIDE] = 0u;
}

// ---- reduce: max coord-norm^2, per-dim max & min ----
__global__ __launch_bounds__(256) void reduce_kernel(
    const float* __restrict__ x, const float* __restrict__ y,
    unsigned* __restrict__ enc) {
  int t = blockIdx.x * 256 + threadIdx.x;     // 0..8191, 4 points each
  bool isx = t < (ROWS / 4);
  int local = (isx ? t : t - ROWS / 4) * 4;
  const float* p = (isx ? x : y) + (size_t)local * 6;
  unsigned e[13];
#pragma unroll
  for (int k = 0; k < 13; ++k) e[k] = 0u;
#pragma unroll
  for (int pt = 0; pt < 4; ++pt) {
    float d[6];
#pragma unroll
    for (int k = 0; k < 6; ++k) d[k] = p[pt * 6 + k];
    unsigned n2 = fenc(d[0] * d[0] + d[1] * d[1] + d[2] * d[2]);
    e[0] = e[0] > n2 ? e[0] : n2;
#pragma unroll
    for (int k = 0; k < 6; ++k) {
      unsigned a = fenc(d[k]), b = fenc(-d[k]);
      e[1 + k] = e[1 + k] > a ? e[1 + k] : a;
      e[7 + k] = e[7 + k] > b ? e[7 + k] : b;
    }
  }
#pragma unroll
  for (int off = 32; off > 0; off >>= 1) {
#pragma unroll
    for (int k = 0; k < 13; ++k) {
      unsigned o = (unsigned)__shfl_xor((int)e[k], off);
      e[k] = e[k] > o ? e[k] : o;
    }
  }
  __shared__ unsigned sh[4][13];
  int wave = threadIdx.x >> 6, lane = threadIdx.x & 63;
  if (lane == 0) {
#pragma unroll
    for (int k = 0; k < 13; ++k) sh[wave][k] = e[k];
  }
  __syncthreads();
  if (threadIdx.x < 13) {
    unsigned v = sh[0][threadIdx.x];
#pragma unroll
    for (int w = 1; w < 4; ++w) v = v > sh[w][threadIdx.x] ? v : sh[w][threadIdx.x];
    atomicMax(&enc[threadIdx.x * ENC_STRIDE], v);
  }
}

// ---- pack: AoS (row side) + SoA (column side) + hh0 ----
__global__ __launch_bounds__(256) void pack_kernel(
    const float* __restrict__ x, const float* __restrict__ y,
    float4* __restrict__ XP, float4* __restrict__ YP,
    float* __restrict__ CXs, float* __restrict__ CYs,
    float* __restrict__ HHX0, float* __restrict__ HHY0,
    const unsigned* __restrict__ enc, float* __restrict__ sc) {
  int idx = blockIdx.x * 256 + threadIdx.x;  // 0..32767
  float maxnorm = sqrtf(fdec(enc[0]));
  float s = 1.0f / (maxnorm + 1e-6f);
  float eps0 = 0.0f;
#pragma unroll
  for (int k = 0; k < 6; ++k) {
    float mx = fdec(enc[(1 + k) * ENC_STRIDE]);
    float mn = -fdec(enc[(7 + k) * ENC_STRIDE]);
    float d = mx - mn;
    eps0 += d * d;
  }
  if (idx == 0) sc[0] = eps0;

  bool isx = idx < ROWS;
  int local = isx ? idx : idx - ROWS;
  const float* p = (isx ? x : y) + (size_t)local * 6;
  float v[6];
  v[0] = p[0] * s; v[1] = p[1] * s; v[2] = p[2] * s;
  v[3] = 0.1f * fminf(fmaxf(p[3], 0.0f), 1.0f);
  v[4] = 0.1f * fminf(fmaxf(p[4], 0.0f), 1.0f);
  v[5] = 0.1f * fminf(fmaxf(p[5], 0.0f), 1.0f);
  float q = v[0]*v[0] + v[1]*v[1] + v[2]*v[2] + v[3]*v[3] + v[4]*v[4] + v[5]*v[5];
  float4* P = isx ? XP : YP;
  P[(size_t)local * 2]     = make_float4(v[0], v[1], v[2], v[3]);
  P[(size_t)local * 2 + 1] = make_float4(v[4], v[5], q, 0.0f);
  float* S = isx ? CXs : CYs;
#pragma unroll
  for (int d = 0; d < 6; ++d) S[d * ROWS + local] = v[d];
  float hh0 = NEG_LOG2M - q * (LOG2E / eps0);
  (isx ? HHX0 : HHY0)[local] = hh0;
}

// ---- fused softmin PAIR: 2048 blocks; block = 16 rows (2 rowgroups of 8),
// ---- each rowgroup by 2 waves (column halves), SoA packed-pair inner loop.
__global__ __launch_bounds__(256) void softmin_pair_kernel(
    const float4* __restrict__ XP, const float4* __restrict__ YP,
    const float* __restrict__ CXs, const float* __restrict__ CYs,
    const float* __restrict__ hhY, const float* __restrict__ hhX,
    const float* __restrict__ prevF, const float* __restrict__ prevG,
    float* __restrict__ outF, float* __restrict__ outG,
    float* __restrict__ hhFo, float* __restrict__ hhGo,
    const float* __restrict__ sc, int eps_sel, int next_sel) {
  int wave = threadIdx.x >> 6, lane = threadIdx.x & 63;
  int rg = wave >> 1, half = wave & 1;
  int grow0 = blockIdx.x * 16 + rg * 8;       // first global row (0..32767)
  int dir = grow0 >> 14;                      // 0: xy, 1: yx
  int lrow0 = grow0 & (ROWS - 1);
  const float4* rows = dir ? YP : XP;
  const float* cols  = dir ? CXs : CYs;       // columns are the OTHER side
  const float* hh    = dir ? hhX : hhY;
  const float* prev  = dir ? prevG : prevF;
  float* out = dir ? outG : outF;
  float* hho = dir ? hhGo : hhFo;

  float eps = eps_sel ? sc[0] : EPS1;
  float sc2 = 2.0f * LOG2E / eps;

  float P[8][6], Q[8];
#pragma unroll
  for (int r = 0; r < 8; ++r) {
    float4 a = rows[(size_t)(lrow0 + r) * 2];
    float4 b = rows[(size_t)(lrow0 + r) * 2 + 1];
    P[r][0] = a.x * sc2; P[r][1] = a.y * sc2; P[r][2] = a.z * sc2;
    P[r][3] = a.w * sc2; P[r][4] = b.x * sc2; P[r][5] = b.y * sc2;
    Q[r] = b.z;
  }

  int cb = (lrow0 >> 12) << 12;               // batch column base
  int jbase = cb + half * 2048 + 4 * lane;    // this lane's first column
  const float* hp = hh + jbase;

  float m[8], s[8];
#pragma unroll
  for (int r = 0; r < 8; ++r) { m[r] = -3.0e38f; s[r] = 0.0f; }

  for (int t = 0; t < 8; ++t) {
    int off = t * 256;
    float4 h4 = *(const float4*)(hp + off);
    f2 H0 = f2{h4.x, h4.y}, H1 = f2{h4.z, h4.w};
    f2 C0[6], C1[6];
#pragma unroll
    for (int d = 0; d < 6; ++d) {
      float4 c4 = *(const float4*)(cols + (size_t)d * ROWS + jbase + off);
      C0[d] = f2{c4.x, c4.y};
      C1[d] = f2{c4.z, c4.w};
    }
#pragma unroll
    for (int r = 0; r < 8; ++r) {
      f2 a0 = H0, a1 = H1;
#pragma unroll
      for (int d = 0; d < 6; ++d) {
        f2 pd = f2{P[r][d], P[r][d]};
        a0 = __builtin_elementwise_fma(C0[d], pd, a0);
        a1 = __builtin_elementwise_fma(C1[d], pd, a1);
      }
      f2 mx2 = __builtin_elementwise_max(a0, a1);
      float gm = fmaxf(mx2.x, mx2.y);
      f2 g2 = f2{gm, gm};
      f2 d0 = a0 - g2, d1 = a1 - g2;
      f2 e2 = f2{fexp2(d0.x), fexp2(d0.y)} + f2{fexp2(d1.x), fexp2(d1.y)};
      float ls = e2.x + e2.y;
      float mn = fmaxf(m[r], gm);
      s[r] = fmaf(s[r], fexp2(m[r] - mn), ls * fexp2(gm - mn));
      m[r] = mn;
    }
  }

  // 64-lane butterfly merge of (m, s) per row
#pragma unroll
  for (int off = 32; off > 0; off >>= 1) {
#pragma unroll
    for (int r = 0; r < 8; ++r) {
      float mo = __shfl_xor(m[r], off);
      float so = __shfl_xor(s[r], off);
      float mn = fmaxf(m[r], mo);
      s[r] = fmaf(s[r], fexp2(m[r] - mn), so * fexp2(mo - mn));
      m[r] = mn;
    }
  }

  // merge the two column-half waves via LDS
  __shared__ float msh[2][8], ssh[2][8];
  if (half == 1 && lane == 0) {
#pragma unroll
    for (int r = 0; r < 8; ++r) { msh[rg][r] = m[r]; ssh[rg][r] = s[r]; }
  }
  __syncthreads();
  if (half == 0 && lane == 0) {
    float inv_next = next_sel ? (1.0f / sc[0]) : (1.0f / EPS1);
#pragma unroll
    for (int r = 0; r < 8; ++r) {
      float mo = msh[rg][r], so = ssh[rg][r];
      float mn = fmaxf(m[r], mo);
      float ss = fmaf(s[r], fexp2(m[r] - mn), so * fexp2(mo - mn));
      int row = lrow0 + r;
      float f_t = Q[r] - eps * LN2 * (mn + flog2(ss));
      float fo = prev ? 0.5f * (prev[row] + f_t) : f_t;
      out[row] = fo;
      if (hho) hho[row] = NEG_LOG2M + (fo - Q[r]) * (inv_next * LOG2E);
    }
  }
}

// ---- final: 10/(B*N) * (sum f_new + sum g_new) ----
__global__ __launch_bounds__(256) void final_kernel(
    const float* __restrict__ FN, const float* __restrict__ GN,
    float* __restrict__ out) {
  float acc = 0.0f;
  for (int i = threadIdx.x; i < ROWS; i += 256) acc += FN[i] + GN[i];
  __shared__ float sh[256];
  sh[threadIdx.x] = acc;
  __syncthreads();
  for (int st = 128; st > 0; st >>= 1) {
    if (threadIdx.x < st) sh[threadIdx.x] += sh[threadIdx.x + st];
    __syncthreads();
  }
  if (threadIdx.x == 0) out[0] = sh[0] * (10.0f / (float)(B_ * N_));
}

extern "C" void kernel_launch(void* const* d_in, const int* in_sizes, int n_in,
                              void* d_out, int out_size, void* d_ws,
                              size_t ws_size, hipStream_t stream) {
  const float* x = (const float*)d_in[0];
  const float* y = (const float*)d_in[1];
  float* out = (float*)d_out;
  float* w = (float*)d_ws;
  unsigned* enc = (unsigned*)d_ws;        // 13 slots at stride 32
  float* sc = w + 448;                    // sc[0] = eps0

  float* base = w + 512;
  float4* XP = (float4*)base;                       // 131072 floats
  float4* YP = (float4*)(base + 131072);            // 131072
  float* CXs = base + 262144;                       // 6*16384 = 98304
  float* CYs = base + 360448;                       // 98304
  float* HHX0 = base + 458752;                      // 16384
  float* HHY0 = base + 475136;                      // 16384
  float* F1 = base + 491520;
  float* G1 = F1 + ROWS;
  float* F2 = G1 + ROWS;
  float* G2 = F2 + ROWS;
  float* HF1 = G2 + ROWS;
  float* HG1 = HF1 + ROWS;
  float* HF2 = HG1 + ROWS;
  float* HG2 = HF2 + ROWS;
  // aliases (lifetime-safe): pair3 outputs reuse pair1 buffers, etc.
  float* F3 = F1;                 // F1 last read by pair 2
  float* G3 = G1;
  float* FN = F2;                 // F2 last read by pair 3
  float* GN = G2;
  float* HF3 = HHX0;              // HHX0 last read by pair 1
  float* HG3 = HHY0;

  init_kernel<<<1, 64, 0, stream>>>(enc);
  reduce_kernel<<<32, 256, 0, stream>>>(x, y, enc);
  pack_kernel<<<PTS_TOTAL / 256, 256, 0, stream>>>(x, y, XP, YP, CXs, CYs,
                                                   HHX0, HHY0, enc, sc);
  dim3 g(2048), blk(256);
  // pair 1: f1 = SM_xy(eps0, hh=HHY0); g1 = SM_yx(eps0, hh=HHX0)
  softmin_pair_kernel<<<g, blk, 0, stream>>>(XP, YP, CXs, CYs, HHY0, HHX0,
                                             nullptr, nullptr, F1, G1, HF1, HG1,
                                             sc, 1, 1);
  // pair 2: f2 = .5(f1+SM_xy(eps0,HG1)); g2 = .5(g1+SM_yx(eps0,HF1))
  softmin_pair_kernel<<<g, blk, 0, stream>>>(XP, YP, CXs, CYs, HG1, HF1, F1, G1,
                                             F2, G2, HF2, HG2, sc, 1, 0);
  // pair 3: f3 = .5(f2+SM_xy(eps1,HG2)); g3 = .5(g2+SM_yx(eps1,HF2))
  softmin_pair_kernel<<<g, blk, 0, stream>>>(XP, YP, CXs, CYs, HG2, HF2, F2, G2,
                                             F3, G3, HF3, HG3, sc, 0, 0);
  // pair 4: f_new = SM_xy(eps1,HG3); g_new = SM_yx(eps1,HF3)
  softmin_pair_kernel<<<g, blk, 0, stream>>>(XP, YP, CXs, CYs, HG3, HF3, nullptr,
                                             nullptr, FN, GN, nullptr, nullptr,
                                             sc, 0, 0);
  final_kernel<<<1, 256, 0, stream>>>(FN, GN, out);
}

// Round 5
// 277.047 us; speedup vs baseline: 1.0723x; 1.0723x over previous
//
#include <hip/hip_runtime.h>

#define B_ 4
#define N_ 4096
#define ROWS (B_ * N_)            // 16384 rows per side
#define PTS_TOTAL (2 * ROWS)      // 32768 points total

#define LOG2E 1.4426950408889634f
#define LN2   0.6931471805599453f
#define EPS1  1e-4f               /* BLUR^P */
#define NEG_LOG2M (-12.0f)        /* -log2(4096) */
#define ENC_STRIDE 32

typedef float f2 __attribute__((ext_vector_type(2)));

__device__ inline unsigned fenc(float f) {
  unsigned u = __float_as_uint(f);
  return (u & 0x80000000u) ? ~u : (u | 0x80000000u);
}
__device__ inline float fdec(unsigned u) {
  return (u & 0x80000000u) ? __uint_as_float(u & 0x7fffffffu)
                           : __uint_as_float(~u);
}
__device__ inline float fexp2(float x) { return __builtin_amdgcn_exp2f(x); }
__device__ inline float flog2(float x) { return __builtin_amdgcn_logf(x); }

__global__ void init_kernel(unsigned* enc) {
  if (threadIdx.x < 13) enc[threadIdx.x * ENC_STRIDE] = 0u;
}

// ---- reduce: 128 blocks, 1 point/thread; butterfly + LDS merge + 13 atomics
__global__ __launch_bounds__(256) void reduce_kernel(
    const float* __restrict__ x, const float* __restrict__ y,
    unsigned* __restrict__ enc) {
  int idx = blockIdx.x * 256 + threadIdx.x;   // 0..32767
  bool isx = idx < ROWS;
  const float* p = (isx ? x : y) + (size_t)(isx ? idx : idx - ROWS) * 6;
  float d[6];
#pragma unroll
  for (int k = 0; k < 6; ++k) d[k] = p[k];
  unsigned e[13];
  e[0] = fenc(d[0] * d[0] + d[1] * d[1] + d[2] * d[2]);
#pragma unroll
  for (int k = 0; k < 6; ++k) {
    e[1 + k] = fenc(d[k]);
    e[7 + k] = fenc(-d[k]);
  }
#pragma unroll
  for (int off = 32; off > 0; off >>= 1) {
#pragma unroll
    for (int k = 0; k < 13; ++k) {
      unsigned o = (unsigned)__shfl_xor((int)e[k], off);
      e[k] = e[k] > o ? e[k] : o;
    }
  }
  __shared__ unsigned sh[4][13];
  int wave = threadIdx.x >> 6, lane = threadIdx.x & 63;
  if (lane == 0) {
#pragma unroll
    for (int k = 0; k < 13; ++k) sh[wave][k] = e[k];
  }
  __syncthreads();
  if (threadIdx.x < 13) {
    unsigned v = sh[0][threadIdx.x];
#pragma unroll
    for (int w = 1; w < 4; ++w) v = v > sh[w][threadIdx.x] ? v : sh[w][threadIdx.x];
    atomicMax(&enc[threadIdx.x * ENC_STRIDE], v);
  }
}

// ---- pack: AoS rows (8f), 24B column records (6f), hh0 ----
__global__ __launch_bounds__(256) void pack_kernel(
    const float* __restrict__ x, const float* __restrict__ y,
    float4* __restrict__ XP, float4* __restrict__ YP,
    float* __restrict__ CX24, float* __restrict__ CY24,
    float* __restrict__ HHX0, float* __restrict__ HHY0,
    const unsigned* __restrict__ enc, float* __restrict__ sc) {
  int idx = blockIdx.x * 256 + threadIdx.x;  // 0..32767
  float maxnorm = sqrtf(fdec(enc[0]));
  float s = 1.0f / (maxnorm + 1e-6f);
  float eps0 = 0.0f;
#pragma unroll
  for (int k = 0; k < 6; ++k) {
    float mx = fdec(enc[(1 + k) * ENC_STRIDE]);
    float mn = -fdec(enc[(7 + k) * ENC_STRIDE]);
    float dd = mx - mn;
    eps0 += dd * dd;
  }
  if (idx == 0) sc[0] = eps0;

  bool isx = idx < ROWS;
  int local = isx ? idx : idx - ROWS;
  const float* p = (isx ? x : y) + (size_t)local * 6;
  float v[6];
  v[0] = p[0] * s; v[1] = p[1] * s; v[2] = p[2] * s;
  v[3] = 0.1f * fminf(fmaxf(p[3], 0.0f), 1.0f);
  v[4] = 0.1f * fminf(fmaxf(p[4], 0.0f), 1.0f);
  v[5] = 0.1f * fminf(fmaxf(p[5], 0.0f), 1.0f);
  float q = v[0]*v[0] + v[1]*v[1] + v[2]*v[2] + v[3]*v[3] + v[4]*v[4] + v[5]*v[5];
  float4* P = isx ? XP : YP;
  P[(size_t)local * 2]     = make_float4(v[0], v[1], v[2], v[3]);
  P[(size_t)local * 2 + 1] = make_float4(v[4], v[5], q, 0.0f);
  float2* C = (float2*)((isx ? CX24 : CY24) + (size_t)local * 6);
  C[0] = make_float2(v[0], v[1]);
  C[1] = make_float2(v[2], v[3]);
  C[2] = make_float2(v[4], v[5]);
  float hh0 = NEG_LOG2M - q * (LOG2E / eps0);
  (isx ? HHX0 : HHY0)[local] = hh0;
}

// ---- fused softmin PAIR: 2048 blocks, 16 rows/block (2 rowgroups of 8),
// ---- each rowgroup split over 2 waves (2048-col halves). AoS 24B columns,
// ---- lane owns 4 consecutive cols per 256-col stripe, float4 hh loads.
__global__ __launch_bounds__(256) void softmin_pair_kernel(
    const float4* __restrict__ XP, const float4* __restrict__ YP,
    const float* __restrict__ CX24, const float* __restrict__ CY24,
    const float* __restrict__ hhY, const float* __restrict__ hhX,
    const float* __restrict__ prevF, const float* __restrict__ prevG,
    float* __restrict__ outF, float* __restrict__ outG,
    float* __restrict__ hhFo, float* __restrict__ hhGo,
    const float* __restrict__ sc, int eps_sel, int next_sel) {
  int wave = threadIdx.x >> 6, lane = threadIdx.x & 63;
  int rg = wave >> 1, half = wave & 1;
  int grow0 = blockIdx.x * 16 + rg * 8;       // first global row (0..32767)
  int dir = grow0 >> 14;                      // 0: xy, 1: yx
  int lrow0 = grow0 & (ROWS - 1);
  const float4* rows = dir ? YP : XP;
  const float* cols  = dir ? CX24 : CY24;
  const float* hh    = dir ? hhX : hhY;
  const float* prev  = dir ? prevG : prevF;
  float* out = dir ? outG : outF;
  float* hho = dir ? hhGo : hhFo;

  float eps = eps_sel ? sc[0] : EPS1;
  float sc2 = 2.0f * LOG2E / eps;

  f2 P01[8], P23[8], P45[8];
#pragma unroll
  for (int r = 0; r < 8; ++r) {
    float4 a = rows[(size_t)(lrow0 + r) * 2];
    float4 b = rows[(size_t)(lrow0 + r) * 2 + 1];
    P01[r] = f2{a.x * sc2, a.y * sc2};
    P23[r] = f2{a.z * sc2, a.w * sc2};
    P45[r] = f2{b.x * sc2, b.y * sc2};
  }

  int cb = (lrow0 >> 12) << 12;               // batch column base
  int jbase = cb + half * 2048 + lane * 4;    // 4 consecutive cols / stripe
  const float4* cpt = (const float4*)(cols + (size_t)jbase * 6);
  const float4* hpt = (const float4*)(hh + jbase);

  float m[8], s[8];
#pragma unroll
  for (int r = 0; r < 8; ++r) { m[r] = -3.0e38f; s[r] = 0.0f; }

  for (int t = 0; t < 8; ++t) {
    float4 h4 = hpt[0];
    float4 c[6];
#pragma unroll
    for (int k = 0; k < 6; ++k) c[k] = cpt[k];
    cpt += 384;                                // 256 cols * 6 floats
    hpt += 64;                                 // 256 floats
    // 12 f2 dim-pairs: col c uses qd[3c..3c+2]
    f2 qd[12];
    qd[0] = f2{c[0].x, c[0].y}; qd[1] = f2{c[0].z, c[0].w};
    qd[2] = f2{c[1].x, c[1].y}; qd[3] = f2{c[1].z, c[1].w};
    qd[4] = f2{c[2].x, c[2].y}; qd[5] = f2{c[2].z, c[2].w};
    qd[6] = f2{c[3].x, c[3].y}; qd[7] = f2{c[3].z, c[3].w};
    qd[8] = f2{c[4].x, c[4].y}; qd[9] = f2{c[4].z, c[4].w};
    qd[10] = f2{c[5].x, c[5].y}; qd[11] = f2{c[5].z, c[5].w};
    float hv[4] = {h4.x, h4.y, h4.z, h4.w};
#pragma unroll
    for (int r = 0; r < 8; ++r) {
      float v[4];
#pragma unroll
      for (int cc = 0; cc < 4; ++cc) {
        f2 acc = f2{hv[cc], 0.0f};
        acc = __builtin_elementwise_fma(qd[3 * cc + 0], P01[r], acc);
        acc = __builtin_elementwise_fma(qd[3 * cc + 1], P23[r], acc);
        acc = __builtin_elementwise_fma(qd[3 * cc + 2], P45[r], acc);
        v[cc] = acc.x + acc.y;
      }
      float gm = fmaxf(fmaxf(v[0], v[1]), fmaxf(v[2], v[3]));
      float ls = (fexp2(v[0] - gm) + fexp2(v[1] - gm)) +
                 (fexp2(v[2] - gm) + fexp2(v[3] - gm));
      // single-exp2 online merge
      float ddm = m[r] - gm;
      float e = fexp2(-fabsf(ddm));
      float sa = fmaf(s[r], e, ls);     // gm > m : rescale old sum
      float sb = fmaf(ls, e, s[r]);     // gm <= m: rescale new chunk
      s[r] = (gm > m[r]) ? sa : sb;
      m[r] = fmaxf(m[r], gm);
    }
  }

  // 64-lane butterfly merge of (m, s) per row
#pragma unroll
  for (int off = 32; off > 0; off >>= 1) {
#pragma unroll
    for (int r = 0; r < 8; ++r) {
      float mo = __shfl_xor(m[r], off);
      float so = __shfl_xor(s[r], off);
      float ddm = m[r] - mo;
      float e = fexp2(-fabsf(ddm));
      float sa = fmaf(s[r], e, so);     // mo > m
      float sb = fmaf(so, e, s[r]);     // mo <= m
      s[r] = (mo > m[r]) ? sa : sb;
      m[r] = fmaxf(m[r], mo);
    }
  }

  // merge the two column-half waves via LDS
  __shared__ float msh[2][8], ssh[2][8];
  if (half == 1 && lane == 0) {
#pragma unroll
    for (int r = 0; r < 8; ++r) { msh[rg][r] = m[r]; ssh[rg][r] = s[r]; }
  }
  __syncthreads();
  if (half == 0 && lane == 0) {
    float inv_next = next_sel ? (1.0f / sc[0]) : (1.0f / EPS1);
#pragma unroll
    for (int r = 0; r < 8; ++r) {
      float mo = msh[rg][r], so = ssh[rg][r];
      float mn = fmaxf(m[r], mo);
      float ss = fmaf(s[r], fexp2(m[r] - mn), so * fexp2(mo - mn));
      int row = lrow0 + r;
      float q = rows[(size_t)row * 2 + 1].z;
      float f_t = q - eps * LN2 * (mn + flog2(ss));
      float fo = prev ? 0.5f * (prev[row] + f_t) : f_t;
      out[row] = fo;
      if (hho) hho[row] = NEG_LOG2M + (fo - q) * (inv_next * LOG2E);
    }
  }
}

// ---- final: 10/(B*N) * (sum f_new + sum g_new) ----
__global__ __launch_bounds__(256) void final_kernel(
    const float* __restrict__ FN, const float* __restrict__ GN,
    float* __restrict__ out) {
  float acc = 0.0f;
  for (int i = threadIdx.x; i < ROWS; i += 256) acc += FN[i] + GN[i];
  __shared__ float sh[256];
  sh[threadIdx.x] = acc;
  __syncthreads();
  for (int st = 128; st > 0; st >>= 1) {
    if (threadIdx.x < st) sh[threadIdx.x] += sh[threadIdx.x + st];
    __syncthreads();
  }
  if (threadIdx.x == 0) out[0] = sh[0] * (10.0f / (float)(B_ * N_));
}

extern "C" void kernel_launch(void* const* d_in, const int* in_sizes, int n_in,
                              void* d_out, int out_size, void* d_ws,
                              size_t ws_size, hipStream_t stream) {
  const float* x = (const float*)d_in[0];
  const float* y = (const float*)d_in[1];
  float* out = (float*)d_out;
  float* w = (float*)d_ws;
  unsigned* enc = (unsigned*)d_ws;        // 13 slots at stride 32
  float* sc = w + 448;                    // sc[0] = eps0

  float* base = w + 512;
  float4* XP = (float4*)base;                       // 131072 floats
  float4* YP = (float4*)(base + 131072);            // 131072
  float* CX24 = base + 262144;                      // 98304
  float* CY24 = base + 360448;                      // 98304
  float* HHX0 = base + 458752;                      // 16384
  float* HHY0 = base + 475136;                      // 16384
  float* F1 = base + 491520;
  float* G1 = F1 + ROWS;
  float* F2 = G1 + ROWS;
  float* G2 = F2 + ROWS;
  float* HF1 = G2 + ROWS;
  float* HG1 = HF1 + ROWS;
  float* HF2 = HG1 + ROWS;
  float* HG2 = HF2 + ROWS;
  // lifetime-safe aliases
  float* F3 = F1;
  float* G3 = G1;
  float* FN = F2;
  float* GN = G2;
  float* HF3 = HHX0;
  float* HG3 = HHY0;

  init_kernel<<<1, 64, 0, stream>>>(enc);
  reduce_kernel<<<PTS_TOTAL / 256, 256, 0, stream>>>(x, y, enc);
  pack_kernel<<<PTS_TOTAL / 256, 256, 0, stream>>>(x, y, XP, YP, CX24, CY24,
                                                   HHX0, HHY0, enc, sc);
  dim3 g(2048), blk(256);
  softmin_pair_kernel<<<g, blk, 0, stream>>>(XP, YP, CX24, CY24, HHY0, HHX0,
                                             nullptr, nullptr, F1, G1, HF1, HG1,
                                             sc, 1, 1);
  softmin_pair_kernel<<<g, blk, 0, stream>>>(XP, YP, CX24, CY24, HG1, HF1, F1,
                                             G1, F2, G2, HF2, HG2, sc, 1, 0);
  softmin_pair_kernel<<<g, blk, 0, stream>>>(XP, YP, CX24, CY24, HG2, HF2, F2,
                                             G2, F3, G3, HF3, HG3, sc, 0, 0);
  softmin_pair_kernel<<<g, blk, 0, stream>>>(XP, YP, CX24, CY24, HG3, HF3,
                                             nullptr, nullptr, FN, GN, nullptr,
                                             nullptr, sc, 0, 0);
  final_kernel<<<1, 256, 0, stream>>>(FN, GN, out);
}

// Round 6
// 215.922 us; speedup vs baseline: 1.3759x; 1.2831x over previous
//
#include <hip/hip_runtime.h>

#define B_ 4
#define N_ 4096
#define ROWS (B_ * N_)            // 16384 rows per side
#define PTS_TOTAL (2 * ROWS)      // 32768 points total

#define LOG2E 1.4426950408889634f
#define LN2   0.6931471805599453f
#define EPS1  1e-4f               /* BLUR^P */
#define NEG_LOG2M (-12.0f)        /* -log2(4096) */
#define ENC_STRIDE 32

typedef float f2 __attribute__((ext_vector_type(2)));

__device__ inline unsigned fenc(float f) {
  unsigned u = __float_as_uint(f);
  return (u & 0x80000000u) ? ~u : (u | 0x80000000u);
}
__device__ inline float fdec(unsigned u) {
  return (u & 0x80000000u) ? __uint_as_float(u & 0x7fffffffu)
                           : __uint_as_float(~u);
}
__device__ inline float fexp2(float x) { return __builtin_amdgcn_exp2f(x); }
__device__ inline float flog2(float x) { return __builtin_amdgcn_logf(x); }

__global__ void init_kernel(unsigned* enc) {
  if (threadIdx.x < 13) enc[threadIdx.x * ENC_STRIDE] = 0u;
}

// ---- reduce: 128 blocks, 1 point/thread; butterfly + LDS merge + 13 atomics
__global__ __launch_bounds__(256) void reduce_kernel(
    const float* __restrict__ x, const float* __restrict__ y,
    unsigned* __restrict__ enc) {
  int idx = blockIdx.x * 256 + threadIdx.x;   // 0..32767
  bool isx = idx < ROWS;
  const float* p = (isx ? x : y) + (size_t)(isx ? idx : idx - ROWS) * 6;
  float d[6];
#pragma unroll
  for (int k = 0; k < 6; ++k) d[k] = p[k];
  unsigned e[13];
  e[0] = fenc(d[0] * d[0] + d[1] * d[1] + d[2] * d[2]);
#pragma unroll
  for (int k = 0; k < 6; ++k) {
    e[1 + k] = fenc(d[k]);
    e[7 + k] = fenc(-d[k]);
  }
#pragma unroll
  for (int off = 32; off > 0; off >>= 1) {
#pragma unroll
    for (int k = 0; k < 13; ++k) {
      unsigned o = (unsigned)__shfl_xor((int)e[k], off);
      e[k] = e[k] > o ? e[k] : o;
    }
  }
  __shared__ unsigned sh[4][13];
  int wave = threadIdx.x >> 6, lane = threadIdx.x & 63;
  if (lane == 0) {
#pragma unroll
    for (int k = 0; k < 13; ++k) sh[wave][k] = e[k];
  }
  __syncthreads();
  if (threadIdx.x < 13) {
    unsigned v = sh[0][threadIdx.x];
#pragma unroll
    for (int w = 1; w < 4; ++w) v = v > sh[w][threadIdx.x] ? v : sh[w][threadIdx.x];
    atomicMax(&enc[threadIdx.x * ENC_STRIDE], v);
  }
}

// ---- pack: AoS rows (8f); columns pair-interleaved (2 cols / 12f record); hh0
__global__ __launch_bounds__(256) void pack_kernel(
    const float* __restrict__ x, const float* __restrict__ y,
    float4* __restrict__ XP, float4* __restrict__ YP,
    float* __restrict__ CX, float* __restrict__ CY,
    float* __restrict__ HHX0, float* __restrict__ HHY0,
    const unsigned* __restrict__ enc, float* __restrict__ sc) {
  int idx = blockIdx.x * 256 + threadIdx.x;  // 0..32767
  float maxnorm = sqrtf(fdec(enc[0]));
  float s = 1.0f / (maxnorm + 1e-6f);
  float eps0 = 0.0f;
#pragma unroll
  for (int k = 0; k < 6; ++k) {
    float mx = fdec(enc[(1 + k) * ENC_STRIDE]);
    float mn = -fdec(enc[(7 + k) * ENC_STRIDE]);
    float dd = mx - mn;
    eps0 += dd * dd;
  }
  if (idx == 0) sc[0] = eps0;

  bool isx = idx < ROWS;
  int local = isx ? idx : idx - ROWS;
  const float* p = (isx ? x : y) + (size_t)local * 6;
  float v[6];
  v[0] = p[0] * s; v[1] = p[1] * s; v[2] = p[2] * s;
  v[3] = 0.1f * fminf(fmaxf(p[3], 0.0f), 1.0f);
  v[4] = 0.1f * fminf(fmaxf(p[4], 0.0f), 1.0f);
  v[5] = 0.1f * fminf(fmaxf(p[5], 0.0f), 1.0f);
  float q = v[0]*v[0] + v[1]*v[1] + v[2]*v[2] + v[3]*v[3] + v[4]*v[4] + v[5]*v[5];
  float4* P = isx ? XP : YP;
  P[(size_t)local * 2]     = make_float4(v[0], v[1], v[2], v[3]);
  P[(size_t)local * 2 + 1] = make_float4(v[4], v[5], q, 0.0f);
  // pair-record: cols (2p,2p+1) -> 12 floats [d0 d0' d1 d1' ... d5 d5']
  float* C = (isx ? CX : CY) + (size_t)(local >> 1) * 12 + (local & 1);
#pragma unroll
  for (int d = 0; d < 6; ++d) C[d * 2] = v[d];
  float hh0 = NEG_LOG2M - q * (LOG2E / eps0);
  (isx ? HHX0 : HHY0)[local] = hh0;
}

// ================= eps0 softmin (pairs 1,2): plain exp2-sum, no max =========
// 2048 blocks; 16 rows/block (2 rowgroups of 8), rowgroup split over 2 waves.
__global__ __launch_bounds__(256) void softsum_pair_kernel(
    const float4* __restrict__ XP, const float4* __restrict__ YP,
    const float* __restrict__ CX, const float* __restrict__ CY,
    const float* __restrict__ hhY, const float* __restrict__ hhX,
    const float* __restrict__ prevF, const float* __restrict__ prevG,
    float* __restrict__ outF, float* __restrict__ outG,
    float* __restrict__ hhFo, float* __restrict__ hhGo,
    const float* __restrict__ sc, int next_sel) {
  int wave = threadIdx.x >> 6, lane = threadIdx.x & 63;
  int rg = wave >> 1, half = wave & 1;
  int grow0 = blockIdx.x * 16 + rg * 8;
  int dir = grow0 >> 14;
  int lrow0 = grow0 & (ROWS - 1);
  const float4* rows = dir ? YP : XP;
  const float* cols  = dir ? CX : CY;
  const float* hh    = dir ? hhX : hhY;
  const float* prev  = dir ? prevG : prevF;
  float* out = dir ? outG : outF;
  float* hho = dir ? hhGo : hhFo;

  float eps = sc[0];
  float sc2 = 2.0f * LOG2E / eps;

  float P[8][6];
#pragma unroll
  for (int r = 0; r < 8; ++r) {
    float4 a = rows[(size_t)(lrow0 + r) * 2];
    float4 b = rows[(size_t)(lrow0 + r) * 2 + 1];
    P[r][0] = a.x * sc2; P[r][1] = a.y * sc2; P[r][2] = a.z * sc2;
    P[r][3] = a.w * sc2; P[r][4] = b.x * sc2; P[r][5] = b.y * sc2;
  }

  int cb = (lrow0 >> 12) << 12;
  int jbase = cb + half * 2048 + lane * 4;
  const float4* cpt = (const float4*)(cols + (size_t)jbase * 6);
  const float4* hpt = (const float4*)(hh + jbase);

  float s[8];
#pragma unroll
  for (int r = 0; r < 8; ++r) s[r] = 0.0f;

  for (int t = 0; t < 8; ++t) {
    float4 h4 = hpt[0];
    float4 c[6];
#pragma unroll
    for (int k = 0; k < 6; ++k) c[k] = cpt[k];
    cpt += 384;  hpt += 64;
    f2 H01 = f2{h4.x, h4.y}, H23 = f2{h4.z, h4.w};
    f2 D0a = f2{c[0].x, c[0].y}, D1a = f2{c[0].z, c[0].w};
    f2 D2a = f2{c[1].x, c[1].y}, D3a = f2{c[1].z, c[1].w};
    f2 D4a = f2{c[2].x, c[2].y}, D5a = f2{c[2].z, c[2].w};
    f2 D0b = f2{c[3].x, c[3].y}, D1b = f2{c[3].z, c[3].w};
    f2 D2b = f2{c[4].x, c[4].y}, D3b = f2{c[4].z, c[4].w};
    f2 D4b = f2{c[5].x, c[5].y}, D5b = f2{c[5].z, c[5].w};
#pragma unroll
    for (int r = 0; r < 8; ++r) {
      f2 v0 = H01, v1 = H23;
      v0 = __builtin_elementwise_fma(D0a, f2{P[r][0], P[r][0]}, v0);
      v1 = __builtin_elementwise_fma(D0b, f2{P[r][0], P[r][0]}, v1);
      v0 = __builtin_elementwise_fma(D1a, f2{P[r][1], P[r][1]}, v0);
      v1 = __builtin_elementwise_fma(D1b, f2{P[r][1], P[r][1]}, v1);
      v0 = __builtin_elementwise_fma(D2a, f2{P[r][2], P[r][2]}, v0);
      v1 = __builtin_elementwise_fma(D2b, f2{P[r][2], P[r][2]}, v1);
      v0 = __builtin_elementwise_fma(D3a, f2{P[r][3], P[r][3]}, v0);
      v1 = __builtin_elementwise_fma(D3b, f2{P[r][3], P[r][3]}, v1);
      v0 = __builtin_elementwise_fma(D4a, f2{P[r][4], P[r][4]}, v0);
      v1 = __builtin_elementwise_fma(D4b, f2{P[r][4], P[r][4]}, v1);
      v0 = __builtin_elementwise_fma(D5a, f2{P[r][5], P[r][5]}, v0);
      v1 = __builtin_elementwise_fma(D5b, f2{P[r][5], P[r][5]}, v1);
      s[r] += (fexp2(v0.x) + fexp2(v0.y)) + (fexp2(v1.x) + fexp2(v1.y));
    }
  }

#pragma unroll
  for (int off = 32; off > 0; off >>= 1) {
#pragma unroll
    for (int r = 0; r < 8; ++r) s[r] += __shfl_xor(s[r], off);
  }

  __shared__ float ssh[2][8];
  if (half == 1 && lane == 0) {
#pragma unroll
    for (int r = 0; r < 8; ++r) ssh[rg][r] = s[r];
  }
  __syncthreads();
  if (half == 0 && lane == 0) {
    float inv_next = next_sel ? (1.0f / sc[0]) : (1.0f / EPS1);
#pragma unroll
    for (int r = 0; r < 8; ++r) {
      float ss = s[r] + ssh[rg][r];
      int row = lrow0 + r;
      float q = rows[(size_t)row * 2 + 1].z;
      float f_t = q - eps * LN2 * flog2(ss);
      float fo = prev ? 0.5f * (prev[row] + f_t) : f_t;
      out[row] = fo;
      if (hho) hho[row] = NEG_LOG2M + (fo - q) * (inv_next * LOG2E);
    }
  }
}

// ================= eps1 softmin (pairs 3,4): pure max, zero exp2 ============
__global__ __launch_bounds__(256) void softmax_pair_kernel(
    const float4* __restrict__ XP, const float4* __restrict__ YP,
    const float* __restrict__ CX, const float* __restrict__ CY,
    const float* __restrict__ hhY, const float* __restrict__ hhX,
    const float* __restrict__ prevF, const float* __restrict__ prevG,
    float* __restrict__ outF, float* __restrict__ outG,
    float* __restrict__ hhFo, float* __restrict__ hhGo,
    const float* __restrict__ sc) {
  int wave = threadIdx.x >> 6, lane = threadIdx.x & 63;
  int rg = wave >> 1, half = wave & 1;
  int grow0 = blockIdx.x * 16 + rg * 8;
  int dir = grow0 >> 14;
  int lrow0 = grow0 & (ROWS - 1);
  const float4* rows = dir ? YP : XP;
  const float* cols  = dir ? CX : CY;
  const float* hh    = dir ? hhX : hhY;
  const float* prev  = dir ? prevG : prevF;
  float* out = dir ? outG : outF;
  float* hho = dir ? hhGo : hhFo;

  const float eps = EPS1;
  float sc2 = 2.0f * LOG2E / eps;

  float P[8][6];
#pragma unroll
  for (int r = 0; r < 8; ++r) {
    float4 a = rows[(size_t)(lrow0 + r) * 2];
    float4 b = rows[(size_t)(lrow0 + r) * 2 + 1];
    P[r][0] = a.x * sc2; P[r][1] = a.y * sc2; P[r][2] = a.z * sc2;
    P[r][3] = a.w * sc2; P[r][4] = b.x * sc2; P[r][5] = b.y * sc2;
  }

  int cb = (lrow0 >> 12) << 12;
  int jbase = cb + half * 2048 + lane * 4;
  const float4* cpt = (const float4*)(cols + (size_t)jbase * 6);
  const float4* hpt = (const float4*)(hh + jbase);

  f2 m2[8];
#pragma unroll
  for (int r = 0; r < 8; ++r) m2[r] = f2{-3.0e38f, -3.0e38f};

  for (int t = 0; t < 8; ++t) {
    float4 h4 = hpt[0];
    float4 c[6];
#pragma unroll
    for (int k = 0; k < 6; ++k) c[k] = cpt[k];
    cpt += 384;  hpt += 64;
    f2 H01 = f2{h4.x, h4.y}, H23 = f2{h4.z, h4.w};
    f2 D0a = f2{c[0].x, c[0].y}, D1a = f2{c[0].z, c[0].w};
    f2 D2a = f2{c[1].x, c[1].y}, D3a = f2{c[1].z, c[1].w};
    f2 D4a = f2{c[2].x, c[2].y}, D5a = f2{c[2].z, c[2].w};
    f2 D0b = f2{c[3].x, c[3].y}, D1b = f2{c[3].z, c[3].w};
    f2 D2b = f2{c[4].x, c[4].y}, D3b = f2{c[4].z, c[4].w};
    f2 D4b = f2{c[5].x, c[5].y}, D5b = f2{c[5].z, c[5].w};
#pragma unroll
    for (int r = 0; r < 8; ++r) {
      f2 v0 = H01, v1 = H23;
      v0 = __builtin_elementwise_fma(D0a, f2{P[r][0], P[r][0]}, v0);
      v1 = __builtin_elementwise_fma(D0b, f2{P[r][0], P[r][0]}, v1);
      v0 = __builtin_elementwise_fma(D1a, f2{P[r][1], P[r][1]}, v0);
      v1 = __builtin_elementwise_fma(D1b, f2{P[r][1], P[r][1]}, v1);
      v0 = __builtin_elementwise_fma(D2a, f2{P[r][2], P[r][2]}, v0);
      v1 = __builtin_elementwise_fma(D2b, f2{P[r][2], P[r][2]}, v1);
      v0 = __builtin_elementwise_fma(D3a, f2{P[r][3], P[r][3]}, v0);
      v1 = __builtin_elementwise_fma(D3b, f2{P[r][3], P[r][3]}, v1);
      v0 = __builtin_elementwise_fma(D4a, f2{P[r][4], P[r][4]}, v0);
      v1 = __builtin_elementwise_fma(D4b, f2{P[r][4], P[r][4]}, v1);
      v0 = __builtin_elementwise_fma(D5a, f2{P[r][5], P[r][5]}, v0);
      v1 = __builtin_elementwise_fma(D5b, f2{P[r][5], P[r][5]}, v1);
      m2[r] = __builtin_elementwise_max(m2[r], __builtin_elementwise_max(v0, v1));
    }
  }

  float m[8];
#pragma unroll
  for (int r = 0; r < 8; ++r) m[r] = fmaxf(m2[r].x, m2[r].y);
#pragma unroll
  for (int off = 32; off > 0; off >>= 1) {
#pragma unroll
    for (int r = 0; r < 8; ++r) m[r] = fmaxf(m[r], __shfl_xor(m[r], off));
  }

  __shared__ float msh[2][8];
  if (half == 1 && lane == 0) {
#pragma unroll
    for (int r = 0; r < 8; ++r) msh[rg][r] = m[r];
  }
  __syncthreads();
  if (half == 0 && lane == 0) {
    const float inv_next = 1.0f / EPS1;
#pragma unroll
    for (int r = 0; r < 8; ++r) {
      float mm = fmaxf(m[r], msh[rg][r]);
      int row = lrow0 + r;
      float q = rows[(size_t)row * 2 + 1].z;
      float f_t = q - eps * LN2 * mm;       // logsumexp == max at eps=1e-4
      float fo = prev ? 0.5f * (prev[row] + f_t) : f_t;
      out[row] = fo;
      if (hho) hho[row] = NEG_LOG2M + (fo - q) * (inv_next * LOG2E);
    }
  }
}

// ---- final: 10/(B*N) * (sum f_new + sum g_new) ----
__global__ __launch_bounds__(256) void final_kernel(
    const float* __restrict__ FN, const float* __restrict__ GN,
    float* __restrict__ out) {
  float acc = 0.0f;
  for (int i = threadIdx.x; i < ROWS; i += 256) acc += FN[i] + GN[i];
  __shared__ float sh[256];
  sh[threadIdx.x] = acc;
  __syncthreads();
  for (int st = 128; st > 0; st >>= 1) {
    if (threadIdx.x < st) sh[threadIdx.x] += sh[threadIdx.x + st];
    __syncthreads();
  }
  if (threadIdx.x == 0) out[0] = sh[0] * (10.0f / (float)(B_ * N_));
}

extern "C" void kernel_launch(void* const* d_in, const int* in_sizes, int n_in,
                              void* d_out, int out_size, void* d_ws,
                              size_t ws_size, hipStream_t stream) {
  const float* x = (const float*)d_in[0];
  const float* y = (const float*)d_in[1];
  float* out = (float*)d_out;
  float* w = (float*)d_ws;
  unsigned* enc = (unsigned*)d_ws;        // 13 slots at stride 32
  float* sc = w + 448;                    // sc[0] = eps0

  float* base = w + 512;
  float4* XP = (float4*)base;                       // 131072 floats
  float4* YP = (float4*)(base + 131072);            // 131072
  float* CX = base + 262144;                        // 98304 (8192 rec * 12)
  float* CY = base + 360448;                        // 98304
  float* HHX0 = base + 458752;                      // 16384
  float* HHY0 = base + 475136;                      // 16384
  float* F1 = base + 491520;
  float* G1 = F1 + ROWS;
  float* F2 = G1 + ROWS;
  float* G2 = F2 + ROWS;
  float* HF1 = G2 + ROWS;
  float* HG1 = HF1 + ROWS;
  float* HF2 = HG1 + ROWS;
  float* HG2 = HF2 + ROWS;
  // lifetime-safe aliases
  float* F3 = F1;
  float* G3 = G1;
  float* FN = F2;
  float* GN = G2;
  float* HF3 = HHX0;
  float* HG3 = HHY0;

  init_kernel<<<1, 64, 0, stream>>>(enc);
  reduce_kernel<<<PTS_TOTAL / 256, 256, 0, stream>>>(x, y, enc);
  pack_kernel<<<PTS_TOTAL / 256, 256, 0, stream>>>(x, y, XP, YP, CX, CY,
                                                   HHX0, HHY0, enc, sc);
  dim3 g(2048), blk(256);
  // pair 1 (eps0): f1 = SM_xy(hh=HHY0); g1 = SM_yx(hh=HHX0); next eps0
  softsum_pair_kernel<<<g, blk, 0, stream>>>(XP, YP, CX, CY, HHY0, HHX0,
                                             nullptr, nullptr, F1, G1, HF1, HG1,
                                             sc, 1);
  // pair 2 (eps0): f2 = .5(f1+SM_xy(HG1)); g2 = .5(g1+SM_yx(HF1)); next eps1
  softsum_pair_kernel<<<g, blk, 0, stream>>>(XP, YP, CX, CY, HG1, HF1, F1, G1,
                                             F2, G2, HF2, HG2, sc, 0);
  // pair 3 (eps1): f3 = .5(f2+SM_xy(HG2)); g3 = .5(g2+SM_yx(HF2))
  softmax_pair_kernel<<<g, blk, 0, stream>>>(XP, YP, CX, CY, HG2, HF2, F2, G2,
                                             F3, G3, HF3, HG3, sc);
  // pair 4 (eps1): f_new = SM_xy(HG3); g_new = SM_yx(HF3)
  softmax_pair_kernel<<<g, blk, 0, stream>>>(XP, YP, CX, CY, HG3, HF3, nullptr,
                                             nullptr, FN, GN, nullptr, nullptr,
                                             sc);
  final_kernel<<<1, 256, 0, stream>>>(FN, GN, out);
}

// Round 7
// 179.871 us; speedup vs baseline: 1.6516x; 1.2004x over previous
//
#include <hip/hip_runtime.h>

#define B_ 4
#define N_ 4096
#define ROWS (B_ * N_)            // 16384 rows per side
#define PTS_TOTAL (2 * ROWS)      // 32768 points total

#define LOG2E 1.4426950408889634f
#define LN2   0.6931471805599453f
#define EPS1  1e-4f               /* BLUR^P */
#define NEG_LOG2M (-12.0f)        /* -log2(4096) */
#define ENC_STRIDE 32

typedef float f2 __attribute__((ext_vector_type(2)));

__device__ inline unsigned fenc(float f) {
  unsigned u = __float_as_uint(f);
  return (u & 0x80000000u) ? ~u : (u | 0x80000000u);
}
__device__ inline float fdec(unsigned u) {
  return (u & 0x80000000u) ? __uint_as_float(u & 0x7fffffffu)
                           : __uint_as_float(~u);
}
__device__ inline float fexp2(float x) { return __builtin_amdgcn_exp2f(x); }
__device__ inline float flog2(float x) { return __builtin_amdgcn_logf(x); }

__global__ void init_kernel(unsigned* enc) {
  if (threadIdx.x < 13) enc[threadIdx.x * ENC_STRIDE] = 0u;
}

// ---- reduce: max coord-norm^2, per-dim max & min (flip-encoded) ----
__global__ __launch_bounds__(256) void reduce_kernel(
    const float* __restrict__ x, const float* __restrict__ y,
    unsigned* __restrict__ enc) {
  int idx = blockIdx.x * 256 + threadIdx.x;   // 0..32767
  bool isx = idx < ROWS;
  const float* p = (isx ? x : y) + (size_t)(isx ? idx : idx - ROWS) * 6;
  float d[6];
#pragma unroll
  for (int k = 0; k < 6; ++k) d[k] = p[k];
  unsigned e[13];
  e[0] = fenc(d[0] * d[0] + d[1] * d[1] + d[2] * d[2]);
#pragma unroll
  for (int k = 0; k < 6; ++k) {
    e[1 + k] = fenc(d[k]);
    e[7 + k] = fenc(-d[k]);
  }
#pragma unroll
  for (int off = 32; off > 0; off >>= 1) {
#pragma unroll
    for (int k = 0; k < 13; ++k) {
      unsigned o = (unsigned)__shfl_xor((int)e[k], off);
      e[k] = e[k] > o ? e[k] : o;
    }
  }
  __shared__ unsigned sh[4][13];
  int wave = threadIdx.x >> 6, lane = threadIdx.x & 63;
  if (lane == 0) {
#pragma unroll
    for (int k = 0; k < 13; ++k) sh[wave][k] = e[k];
  }
  __syncthreads();
  if (threadIdx.x < 13) {
    unsigned v = sh[0][threadIdx.x];
#pragma unroll
    for (int w = 1; w < 4; ++w) v = v > sh[w][threadIdx.x] ? v : sh[w][threadIdx.x];
    atomicMax(&enc[threadIdx.x * ENC_STRIDE], v);
  }
}

// ---- pack: AoS rows (8f); columns pair-interleaved (2 cols / 12f); hh0 ----
__global__ __launch_bounds__(256) void pack_kernel(
    const float* __restrict__ x, const float* __restrict__ y,
    float4* __restrict__ XP, float4* __restrict__ YP,
    float* __restrict__ CX, float* __restrict__ CY,
    float* __restrict__ HHX0, float* __restrict__ HHY0,
    const unsigned* __restrict__ enc, float* __restrict__ sc) {
  int idx = blockIdx.x * 256 + threadIdx.x;  // 0..32767
  float maxnorm = sqrtf(fdec(enc[0]));
  float s = 1.0f / (maxnorm + 1e-6f);
  float eps0 = 0.0f;
#pragma unroll
  for (int k = 0; k < 6; ++k) {
    float mx = fdec(enc[(1 + k) * ENC_STRIDE]);
    float mn = -fdec(enc[(7 + k) * ENC_STRIDE]);
    float dd = mx - mn;
    eps0 += dd * dd;
  }
  if (idx == 0) sc[0] = eps0;

  bool isx = idx < ROWS;
  int local = isx ? idx : idx - ROWS;
  const float* p = (isx ? x : y) + (size_t)local * 6;
  float v[6];
  v[0] = p[0] * s; v[1] = p[1] * s; v[2] = p[2] * s;
  v[3] = 0.1f * fminf(fmaxf(p[3], 0.0f), 1.0f);
  v[4] = 0.1f * fminf(fmaxf(p[4], 0.0f), 1.0f);
  v[5] = 0.1f * fminf(fmaxf(p[5], 0.0f), 1.0f);
  float q = v[0]*v[0] + v[1]*v[1] + v[2]*v[2] + v[3]*v[3] + v[4]*v[4] + v[5]*v[5];
  float4* P = isx ? XP : YP;
  P[(size_t)local * 2]     = make_float4(v[0], v[1], v[2], v[3]);
  P[(size_t)local * 2 + 1] = make_float4(v[4], v[5], q, 0.0f);
  float* C = (isx ? CX : CY) + (size_t)(local >> 1) * 12 + (local & 1);
#pragma unroll
  for (int d = 0; d < 6; ++d) C[d * 2] = v[d];
  float hh0 = NEG_LOG2M - q * (LOG2E / eps0);
  (isx ? HHX0 : HHY0)[local] = hh0;
}

// ==== eps0 softmin via 2nd-order Taylor moments ============================
// moments: W = sum w_j, M1 = sum w_j c_j (6), M2 = sum w_j c_j c_j^T (21),
// w_j = 2^hh_j.  8 blocks = 2 sides x 4 batches.
__global__ __launch_bounds__(256) void mom_kernel(
    const float* __restrict__ CX, const float* __restrict__ CY,
    const float* __restrict__ hhX, const float* __restrict__ hhY,
    float* __restrict__ MOMX, float* __restrict__ MOMY) {
  int side = blockIdx.x >> 2, batch = blockIdx.x & 3;
  const float* C = side ? CY : CX;
  const float* hh = side ? hhY : hhX;
  float* M = (side ? MOMY : MOMX) + batch * 32;
  float acc[28];
#pragma unroll
  for (int k = 0; k < 28; ++k) acc[k] = 0.0f;
  for (int k = 0; k < 16; ++k) {
    int j = batch * 4096 + k * 256 + threadIdx.x;
    float w = fexp2(hh[j]);
    const float* cp = C + (size_t)(j >> 1) * 12 + (j & 1);
    float c[6];
#pragma unroll
    for (int d = 0; d < 6; ++d) c[d] = cp[2 * d];
    acc[0] += w;
    int kk = 1;
#pragma unroll
    for (int d = 0; d < 6; ++d) acc[kk++] += w * c[d];
#pragma unroll
    for (int d = 0; d < 6; ++d) {
      float wc = w * c[d];
#pragma unroll
      for (int e = d; e < 6; ++e) acc[kk++] += wc * c[e];
    }
  }
  int wave = threadIdx.x >> 6, lane = threadIdx.x & 63;
#pragma unroll
  for (int off = 32; off > 0; off >>= 1) {
#pragma unroll
    for (int k = 0; k < 28; ++k) acc[k] += __shfl_xor(acc[k], off);
  }
  __shared__ float sh[4][28];
  if (lane == 0) {
#pragma unroll
    for (int k = 0; k < 28; ++k) sh[wave][k] = acc[k];
  }
  __syncthreads();
  if (threadIdx.x < 28)
    M[threadIdx.x] = (sh[0][threadIdx.x] + sh[1][threadIdx.x]) +
                     (sh[2][threadIdx.x] + sh[3][threadIdx.x]);
}

// rows: f = q - eps*ln2*log2(W + ln2*(p.M1) + ln2^2/2 * p^T M2 p)
__global__ __launch_bounds__(256) void rows_kernel(
    const float4* __restrict__ XP, const float4* __restrict__ YP,
    const float* __restrict__ MOMX, const float* __restrict__ MOMY,
    const float* __restrict__ prevF, const float* __restrict__ prevG,
    float* __restrict__ outF, float* __restrict__ outG,
    float* __restrict__ hhFo, float* __restrict__ hhGo,
    const float* __restrict__ sc, int next_sel) {
  int g = blockIdx.x * 256 + threadIdx.x;     // 0..32767
  int side = g >> 14, lrow = g & (ROWS - 1), b = lrow >> 12;
  const float4* rows = side ? YP : XP;
  const float* M = (side ? MOMX : MOMY) + b * 32;   // opposite-side moments
  const float* prev = side ? prevG : prevF;
  float* out = side ? outG : outF;
  float* hho = side ? hhGo : hhFo;
  float eps = sc[0];
  float sc2 = 2.0f * LOG2E / eps;
  float4 a = rows[(size_t)lrow * 2];
  float4 bb = rows[(size_t)lrow * 2 + 1];
  float p[6] = {a.x * sc2, a.y * sc2, a.z * sc2,
                a.w * sc2, bb.x * sc2, bb.y * sc2};
  float q = bb.z;
  float W = M[0];
  float t1 = 0.0f;
#pragma unroll
  for (int d = 0; d < 6; ++d) t1 += p[d] * M[1 + d];
  float t2 = 0.0f;
  int kk = 7;
#pragma unroll
  for (int d = 0; d < 6; ++d) {
#pragma unroll
    for (int e = d; e < 6; ++e) {
      float coef = (d == e) ? 1.0f : 2.0f;
      t2 += coef * p[d] * p[e] * M[kk];
      kk++;
    }
  }
  float S = W + LN2 * t1 + (0.5f * LN2 * LN2) * t2;
  float f_t = q - eps * LN2 * flog2(S);
  float fo = prev ? 0.5f * (prev[lrow] + f_t) : f_t;
  out[lrow] = fo;
  float inv_next = next_sel ? (1.0f / sc[0]) : (1.0f / EPS1);
  hho[lrow] = NEG_LOG2M + (fo - q) * (inv_next * LOG2E);
}

// ==== eps1 softmin (pairs 3,4): pure max; 16 rows/wave, 2048-col halves ====
__global__ __launch_bounds__(256) void softmax_pair_kernel(
    const float4* __restrict__ XP, const float4* __restrict__ YP,
    const float* __restrict__ CX, const float* __restrict__ CY,
    const float* __restrict__ hhY, const float* __restrict__ hhX,
    const float* __restrict__ prevF, const float* __restrict__ prevG,
    float* __restrict__ outF, float* __restrict__ outG,
    float* __restrict__ hhFo, float* __restrict__ hhGo) {
  int wave = threadIdx.x >> 6, lane = threadIdx.x & 63;
  int task = blockIdx.x * 4 + wave;           // 0..4095
  int rg = task >> 1, half = task & 1;        // rg 0..2047
  int rgl = wave >> 1;                        // rowgroup within block
  int grow0 = rg * 16;
  int dir = grow0 >> 14;
  int lrow0 = grow0 & (ROWS - 1);
  const float4* rows = dir ? YP : XP;
  const float* cols  = dir ? CX : CY;
  const float* hh    = dir ? hhX : hhY;
  const float* prev  = dir ? prevG : prevF;
  float* out = dir ? outG : outF;
  float* hho = dir ? hhGo : hhFo;

  const float eps = EPS1;
  const float sc2 = 2.0f * LOG2E / EPS1;

  float P[16][6];
#pragma unroll
  for (int r = 0; r < 16; ++r) {
    float4 a = rows[(size_t)(lrow0 + r) * 2];
    float4 b = rows[(size_t)(lrow0 + r) * 2 + 1];
    P[r][0] = a.x * sc2; P[r][1] = a.y * sc2; P[r][2] = a.z * sc2;
    P[r][3] = a.w * sc2; P[r][4] = b.x * sc2; P[r][5] = b.y * sc2;
  }

  int cb = (lrow0 >> 12) << 12;
  int rec0 = (cb >> 1) + half * 1024 + lane;  // pair-record index
  const float4* cpt = (const float4*)(cols + (size_t)rec0 * 12);
  const float2* hpt = (const float2*)(hh + cb) + half * 1024 + lane;

  f2 m2[16];
#pragma unroll
  for (int r = 0; r < 16; ++r) m2[r] = f2{-3.0e38f, -3.0e38f};

  for (int t = 0; t < 16; ++t) {
    float4 c0 = cpt[0], c1 = cpt[1], c2 = cpt[2];
    float2 h2 = hpt[0];
    cpt += 192;  hpt += 64;
    f2 H = f2{h2.x, h2.y};
    f2 D0 = f2{c0.x, c0.y}, D1 = f2{c0.z, c0.w};
    f2 D2 = f2{c1.x, c1.y}, D3 = f2{c1.z, c1.w};
    f2 D4 = f2{c2.x, c2.y}, D5 = f2{c2.z, c2.w};
#pragma unroll
    for (int r = 0; r < 16; ++r) {
      f2 v = H;
      v = __builtin_elementwise_fma(D0, f2{P[r][0], P[r][0]}, v);
      v = __builtin_elementwise_fma(D1, f2{P[r][1], P[r][1]}, v);
      v = __builtin_elementwise_fma(D2, f2{P[r][2], P[r][2]}, v);
      v = __builtin_elementwise_fma(D3, f2{P[r][3], P[r][3]}, v);
      v = __builtin_elementwise_fma(D4, f2{P[r][4], P[r][4]}, v);
      v = __builtin_elementwise_fma(D5, f2{P[r][5], P[r][5]}, v);
      m2[r] = __builtin_elementwise_max(m2[r], v);
    }
  }

  float m[16];
#pragma unroll
  for (int r = 0; r < 16; ++r) m[r] = fmaxf(m2[r].x, m2[r].y);
#pragma unroll
  for (int off = 32; off > 0; off >>= 1) {
#pragma unroll
    for (int r = 0; r < 16; ++r) m[r] = fmaxf(m[r], __shfl_xor(m[r], off));
  }

  __shared__ float msh[2][16];
  if (half == 1 && lane == 0) {
#pragma unroll
    for (int r = 0; r < 16; ++r) msh[rgl][r] = m[r];
  }
  __syncthreads();
  if (half == 0 && lane == 0) {
    const float inv_next = 1.0f / EPS1;
#pragma unroll
    for (int r = 0; r < 16; ++r) {
      float mm = fmaxf(m[r], msh[rgl][r]);
      int row = lrow0 + r;
      float q = rows[(size_t)row * 2 + 1].z;
      float f_t = q - eps * LN2 * mm;     // logsumexp == max at eps=1e-4
      float fo = prev ? 0.5f * (prev[row] + f_t) : f_t;
      out[row] = fo;
      if (hho) hho[row] = NEG_LOG2M + (fo - q) * (inv_next * LOG2E);
    }
  }
}

// ---- final: 10/(B*N) * (sum f_new + sum g_new) ----
__global__ __launch_bounds__(256) void final_kernel(
    const float* __restrict__ FN, const float* __restrict__ GN,
    float* __restrict__ out) {
  float acc = 0.0f;
  for (int i = threadIdx.x; i < ROWS; i += 256) acc += FN[i] + GN[i];
  __shared__ float sh[256];
  sh[threadIdx.x] = acc;
  __syncthreads();
  for (int st = 128; st > 0; st >>= 1) {
    if (threadIdx.x < st) sh[threadIdx.x] += sh[threadIdx.x + st];
    __syncthreads();
  }
  if (threadIdx.x == 0) out[0] = sh[0] * (10.0f / (float)(B_ * N_));
}

extern "C" void kernel_launch(void* const* d_in, const int* in_sizes, int n_in,
                              void* d_out, int out_size, void* d_ws,
                              size_t ws_size, hipStream_t stream) {
  const float* x = (const float*)d_in[0];
  const float* y = (const float*)d_in[1];
  float* out = (float*)d_out;
  float* w = (float*)d_ws;
  unsigned* enc = (unsigned*)d_ws;        // 13 slots at stride 32
  float* sc = w + 448;                    // sc[0] = eps0

  float* base = w + 512;
  float4* XP = (float4*)base;                       // 131072 floats
  float4* YP = (float4*)(base + 131072);            // 131072
  float* CX = base + 262144;                        // 98304 (8192 rec * 12)
  float* CY = base + 360448;                        // 98304
  float* HHX0 = base + 458752;                      // 16384
  float* HHY0 = base + 475136;                      // 16384
  float* F1 = base + 491520;
  float* G1 = F1 + ROWS;
  float* F2 = G1 + ROWS;
  float* G2 = F2 + ROWS;
  float* HF1 = G2 + ROWS;
  float* HG1 = HF1 + ROWS;
  float* HF2 = HG1 + ROWS;
  float* HG2 = HF2 + ROWS;
  float* MOMX = HG2 + ROWS;                         // 4*32
  float* MOMY = MOMX + 128;                         // 4*32
  // lifetime-safe aliases
  float* F3 = F1;
  float* G3 = G1;
  float* FN = F2;
  float* GN = G2;
  float* HF3 = HHX0;
  float* HG3 = HHY0;

  init_kernel<<<1, 64, 0, stream>>>(enc);
  reduce_kernel<<<PTS_TOTAL / 256, 256, 0, stream>>>(x, y, enc);
  pack_kernel<<<PTS_TOTAL / 256, 256, 0, stream>>>(x, y, XP, YP, CX, CY,
                                                   HHX0, HHY0, enc, sc);
  // pair 1 (eps0, analytic): f1,g1 + HF1,HG1 (next eps0)
  mom_kernel<<<8, 256, 0, stream>>>(CX, CY, HHX0, HHY0, MOMX, MOMY);
  rows_kernel<<<PTS_TOTAL / 256, 256, 0, stream>>>(XP, YP, MOMX, MOMY, nullptr,
                                                   nullptr, F1, G1, HF1, HG1,
                                                   sc, 1);
  // pair 2 (eps0, analytic): f2,g2 + HF2,HG2 (next eps1)
  mom_kernel<<<8, 256, 0, stream>>>(CX, CY, HF1, HG1, MOMX, MOMY);
  rows_kernel<<<PTS_TOTAL / 256, 256, 0, stream>>>(XP, YP, MOMX, MOMY, F1, G1,
                                                   F2, G2, HF2, HG2, sc, 0);
  // pair 3 (eps1, max): f3 = .5(f2+SM_xy(HG2)); g3 = .5(g2+SM_yx(HF2))
  softmax_pair_kernel<<<1024, 256, 0, stream>>>(XP, YP, CX, CY, HG2, HF2, F2,
                                                G2, F3, G3, HF3, HG3);
  // pair 4 (eps1, max): f_new = SM_xy(HG3); g_new = SM_yx(HF3)
  softmax_pair_kernel<<<1024, 256, 0, stream>>>(XP, YP, CX, CY, HG3, HF3,
                                                nullptr, nullptr, FN, GN,
                                                nullptr, nullptr);
  final_kernel<<<1, 256, 0, stream>>>(FN, GN, out);
}